// Round 25
// baseline (814.124 us; speedup 1.0000x reference)
//
#include <hip/hip_runtime.h>
#include <hip/hip_bf16.h>

#define SDIM 128
#define NCOL 16384          // SDIM*SDIM
#define ROWS_TOTAL 4096
#define CHUNK 1024
#define RT_PC 64            // row-tiles per chunk
#define NCHUNK 4

using bf16x8 = __attribute__((ext_vector_type(8))) __bf16;
using su8    = __attribute__((ext_vector_type(8))) ushort;
using f32x4  = __attribute__((ext_vector_type(4))) float;

__device__ __forceinline__ ushort f2bf(float f) {
  __hip_bfloat16 h = __float2bfloat16(f);
  union { __hip_bfloat16 h; ushort u; } c; c.h = h;
  return c.u;
}

// ---- prep: L,R f32 -> bf16 in fragment-major layout ----
__global__ __launch_bounds__(256) void k_prep(const float* __restrict__ L,
                                              const float* __restrict__ R,
                                              ushort* __restrict__ Lt,
                                              ushort* __restrict__ Rt) {
  int id = blockIdx.x * 256 + threadIdx.x;
  const float* in = (id < 262144) ? L : R;
  ushort* outp    = (id < 262144) ? Lt : Rt;
  int t  = id & 262143;
  int t1 = t >> 11;
  int ks = (t >> 9) & 3;
  int tb = (t >> 6) & 7;
  int g  = (t >> 4) & 3;
  int tl = t & 15;
  const float* src = in + (size_t)(t1 * 128 + tb * 16 + tl) * 128 + ks * 32 + g * 8;
  float4 a = *reinterpret_cast<const float4*>(src);
  float4 b = *reinterpret_cast<const float4*>(src + 4);
  su8 o;
  o[0] = f2bf(a.x); o[1] = f2bf(a.y); o[2] = f2bf(a.z); o[3] = f2bf(a.w);
  o[4] = f2bf(b.x); o[5] = f2bf(b.y); o[6] = f2bf(b.z); o[7] = f2bf(b.w);
  *reinterpret_cast<su8*>(outp + (size_t)t * 8) = o;
}

// ======== stage1: 512 thr, block = 16 rows x 16 m (mg2 = bid&7 = XCD) ========
// Staging: 4 consecutive lanes read the 4 quarters of ONE 64B line (R22, -21us).
// x loads + T3 stores NON-TEMPORAL (ext_vector types): streams pass through L2
// without evicting the XCD-pinned 512KB Lt slice.
__global__ __launch_bounds__(512, 2) void k_s1(const float* __restrict__ x,
                                               const ushort* __restrict__ Lt,
                                               ushort* __restrict__ T3) {
  __shared__ __align__(16) ushort sh[32768];
  int tid = threadIdx.x;
  unsigned bid = blockIdx.x;
  int mg2 = bid & 7;
  int rt  = bid >> 3;              // chunk-local
  int row0 = rt * 16;
  int m0 = mg2 * 16;

  // ---- stage x slice [16m][16r][128k] into LDS (f32->bf16), swizzled on r ----
  {
    int r  = tid >> 5;             // 0..15
    int q  = tid & 3;              // 16B quarter: m sub-block q*4..q*4+4
    int k8 = (tid >> 2) & 7;       // thread covers k = k8*16 .. k8*16+15
    const float* base = x + (size_t)(row0 + r) * NCOL + (size_t)(k8 * 16) * SDIM + m0 + q * 4;
    ushort vm[4][16];              // [mm][kk]
#pragma unroll
    for (int kk = 0; kk < 16; ++kk) {
      f32x4 a = __builtin_nontemporal_load(
          reinterpret_cast<const f32x4*>(base + (size_t)kk * SDIM));
      vm[0][kk] = f2bf(a[0]); vm[1][kk] = f2bf(a[1]);
      vm[2][kk] = f2bf(a[2]); vm[3][kk] = f2bf(a[3]);
    }
    int swz_w = (r & 7) << 3;
#pragma unroll
    for (int mm = 0; mm < 4; ++mm) {
      int mloc = q * 4 + mm;
      int ebase = ((mloc * 16 + r) << 7) + k8 * 16;
      su8 lo, hi;
#pragma unroll
      for (int e = 0; e < 8; ++e) { lo[e] = vm[mm][e]; hi[e] = vm[mm][8 + e]; }
      *reinterpret_cast<su8*>(&sh[ebase ^ swz_w]) = lo;
      *reinterpret_cast<su8*>(&sh[(ebase + 8) ^ swz_w]) = hi;
    }
  }
  __syncthreads();

  int wave = tid >> 6, lane = tid & 63;
  int l15 = lane & 15, g = lane >> 4;
  int swz = (l15 & 7) << 3;
  int w4 = wave & 3, mgh = wave >> 2;      // j-quadrant, m-half
  int m0h = m0 + mgh * 8;
  const ushort* Lp = Lt + ((size_t)m0h * 32 + (size_t)w4 * 2) * 512 + (size_t)lane * 8;

  f32x4 st[2][8];
#pragma unroll
  for (int m = 0; m < 8; ++m) {
    int mloc = mgh * 8 + m;
    bf16x8 xf[4];
#pragma unroll
    for (int ks = 0; ks < 4; ++ks) {
      int e = ((mloc * 16 + l15) << 7) + ks * 32 + g * 8;
      xf[ks] = *reinterpret_cast<const bf16x8*>(&sh[e ^ swz]);
    }
    f32x4 a0 = {0.f, 0.f, 0.f, 0.f};
    f32x4 a1 = {0.f, 0.f, 0.f, 0.f};
#pragma unroll
    for (int ks = 0; ks < 4; ++ks) {
      bf16x8 l0 = *reinterpret_cast<const bf16x8*>(Lp + (size_t)((m * 4 + ks) * 8 + 0) * 512);
      bf16x8 l1 = *reinterpret_cast<const bf16x8*>(Lp + (size_t)((m * 4 + ks) * 8 + 1) * 512);
      a0 = __builtin_amdgcn_mfma_f32_16x16x32_bf16(xf[ks], l0, a0, 0, 0, 0);
      a1 = __builtin_amdgcn_mfma_f32_16x16x32_bf16(xf[ks], l1, a1, 0, 0, 0);
    }
    st[0][m] = a0;
    st[1][m] = a1;
  }

  int mg = mg2 * 2 + mgh;
  int ks1 = mg >> 2, g2 = mg & 3;
#pragma unroll
  for (int jt = 0; jt < 2; ++jt) {
    int j = w4 * 32 + jt * 16 + l15;
#pragma unroll
    for (int v = 0; v < 4; ++v) {
      int rr = g * 4 + v;
      su8 o;
      o[0] = f2bf(st[jt][0][v]); o[1] = f2bf(st[jt][1][v]);
      o[2] = f2bf(st[jt][2][v]); o[3] = f2bf(st[jt][3][v]);
      o[4] = f2bf(st[jt][4][v]); o[5] = f2bf(st[jt][5][v]);
      o[6] = f2bf(st[jt][6][v]); o[7] = f2bf(st[jt][7][v]);
      size_t a = (((size_t)(rt * 128 + j) * 4 + ks1) * 64 + g2 * 16 + rr) * 8;
      __builtin_nontemporal_store(o, reinterpret_cast<su8*>(T3 + a));
    }
  }
}

// ======== stage2: 512 thr, jg = bid&7 pinned to XCD; grid = RT_PC*8 ========
// T3 slice staged via async global_load_lds; out stores NON-TEMPORAL so the
// out stream doesn't evict the XCD-pinned 512KB R slice from L2.
__global__ __launch_bounds__(512, 2) void k_s2(const ushort* __restrict__ T3,
                                               const ushort* __restrict__ Rt,
                                               float* __restrict__ out) {
  __shared__ __align__(16) ushort sh[32768];
  int tid = threadIdx.x;
  unsigned bid = blockIdx.x;
  int jg = bid & 7;
  int rt = bid >> 3;
  int row0 = rt * 16;
  int j0 = jg * 16;

  int wave = tid >> 6, lane = tid & 63;
  int l15 = lane & 15, g = lane >> 4;
  int ibase = wave * 16;

  {
    const ushort* s = T3 + (size_t)(rt * 128 + j0) * 4 * 512;
#if __has_builtin(__builtin_amdgcn_global_load_lds)
#pragma unroll
    for (int q = 0; q < 8; ++q) {
      int off = q * 512 + tid;
      __builtin_amdgcn_global_load_lds(
          (const __attribute__((address_space(1))) unsigned int*)(s + (size_t)off * 8),
          (__attribute__((address_space(3))) unsigned int*)(sh + (size_t)off * 8),
          16, 0, 0);
    }
#else
    const su8* s8 = reinterpret_cast<const su8*>(s);
    su8* d8 = reinterpret_cast<su8*>(sh);
#pragma unroll
    for (int q = 0; q < 8; ++q)
      d8[q * 512 + tid] = s8[q * 512 + tid];
#endif
  }
  __syncthreads();

  f32x4 acc[16];
#pragma unroll
  for (int jj = 0; jj < 16; ++jj) acc[jj] = {0.f, 0.f, 0.f, 0.f};

  const ushort* Rp = Rt + ((size_t)j0 * 32 + wave) * 512 + (size_t)lane * 8;
  const ushort* tp = sh + (size_t)lane * 8;

#pragma unroll
  for (int jj = 0; jj < 16; ++jj) {
#pragma unroll
    for (int ks = 0; ks < 4; ++ks) {
      bf16x8 af = *reinterpret_cast<const bf16x8*>(tp + (size_t)(jj * 4 + ks) * 512);
      bf16x8 bf = *reinterpret_cast<const bf16x8*>(Rp + (size_t)(jj * 32 + ks * 8) * 512);
      acc[jj] = __builtin_amdgcn_mfma_f32_16x16x32_bf16(af, bf, acc[jj], 0, 0, 0);
    }
  }

#pragma unroll
  for (int v = 0; v < 4; ++v) {
    float* dst = out + (size_t)(row0 + g * 4 + v) * NCOL + (size_t)(ibase + l15) * SDIM + j0;
#pragma unroll
    for (int q = 0; q < 4; ++q) {
      f32x4 o; o[0] = acc[q * 4 + 0][v]; o[1] = acc[q * 4 + 1][v];
               o[2] = acc[q * 4 + 2][v]; o[3] = acc[q * 4 + 3][v];
      __builtin_nontemporal_store(o, reinterpret_cast<f32x4*>(dst + q * 4));
    }
  }
}

extern "C" void kernel_launch(void* const* d_in, const int* in_sizes, int n_in,
                              void* d_out, int out_size, void* d_ws, size_t ws_size,
                              hipStream_t stream) {
  const float* x = (const float*)d_in[0];
  const float* L = (const float*)d_in[1];
  const float* R = (const float*)d_in[2];
  float* out = (float*)d_out;

  ushort* Lt = (ushort*)d_ws;
  ushort* Rt = Lt + 2097152;
  ushort* T3 = Rt + 2097152;      // 32 MB chunk buffer (L3-resident round-trip)

  k_prep<<<2048, 256, 0, stream>>>(L, R, Lt, Rt);

  for (int c = 0; c < NCHUNK; ++c) {
    const float* xc = x + (size_t)c * CHUNK * NCOL;
    float* oc = out + (size_t)c * CHUNK * NCOL;
    k_s1<<<dim3(RT_PC * 8), 512, 0, stream>>>(xc, Lt, T3);
    k_s2<<<dim3(RT_PC * 8), 512, 0, stream>>>(T3, Rt, oc);
  }
}

// Round 26
// 272.917 us; speedup vs baseline: 2.9830x; 2.9830x over previous
//
#include <hip/hip_runtime.h>
#include <hip/hip_bf16.h>

#define SDIM 128
#define NCOL 16384          // SDIM*SDIM
#define ROWS_TOTAL 4096
#define CHUNK 1024
#define RT_PC 64            // row-tiles per chunk
#define NCHUNK 4

using bf16x8 = __attribute__((ext_vector_type(8))) __bf16;
using su8    = __attribute__((ext_vector_type(8))) ushort;
using f32x4  = __attribute__((ext_vector_type(4))) float;

__device__ __forceinline__ ushort f2bf(float f) {
  __hip_bfloat16 h = __float2bfloat16(f);
  union { __hip_bfloat16 h; ushort u; } c; c.h = h;
  return c.u;
}

// ---- prep: L,R f32 -> bf16 in fragment-major layout ----
__global__ __launch_bounds__(256) void k_prep(const float* __restrict__ L,
                                              const float* __restrict__ R,
                                              ushort* __restrict__ Lt,
                                              ushort* __restrict__ Rt) {
  int id = blockIdx.x * 256 + threadIdx.x;
  const float* in = (id < 262144) ? L : R;
  ushort* outp    = (id < 262144) ? Lt : Rt;
  int t  = id & 262143;
  int t1 = t >> 11;
  int ks = (t >> 9) & 3;
  int tb = (t >> 6) & 7;
  int g  = (t >> 4) & 3;
  int tl = t & 15;
  const float* src = in + (size_t)(t1 * 128 + tb * 16 + tl) * 128 + ks * 32 + g * 8;
  float4 a = *reinterpret_cast<const float4*>(src);
  float4 b = *reinterpret_cast<const float4*>(src + 4);
  su8 o;
  o[0] = f2bf(a.x); o[1] = f2bf(a.y); o[2] = f2bf(a.z); o[3] = f2bf(a.w);
  o[4] = f2bf(b.x); o[5] = f2bf(b.y); o[6] = f2bf(b.z); o[7] = f2bf(b.w);
  *reinterpret_cast<su8*>(outp + (size_t)t * 8) = o;
}

// ======== stage1: 512 thr, block = 16 rows x 16 m (mg2 = bid&7 = XCD) ========
// Staging: 4 consecutive lanes read the 4 quarters of ONE 64B line (R22, -21us).
__global__ __launch_bounds__(512, 2) void k_s1(const float* __restrict__ x,
                                               const ushort* __restrict__ Lt,
                                               ushort* __restrict__ T3) {
  __shared__ __align__(16) ushort sh[32768];
  int tid = threadIdx.x;
  unsigned bid = blockIdx.x;
  int mg2 = bid & 7;
  int rt  = bid >> 3;              // chunk-local
  int row0 = rt * 16;
  int m0 = mg2 * 16;

  // ---- stage x slice [16m][16r][128k] into LDS (f32->bf16), swizzled on r ----
  {
    int r  = tid >> 5;             // 0..15
    int q  = tid & 3;              // 16B quarter: m sub-block q*4..q*4+4
    int k8 = (tid >> 2) & 7;       // thread covers k = k8*16 .. k8*16+15
    const float* base = x + (size_t)(row0 + r) * NCOL + (size_t)(k8 * 16) * SDIM + m0 + q * 4;
    ushort vm[4][16];              // [mm][kk]
#pragma unroll
    for (int kk = 0; kk < 16; ++kk) {
      float4 a = *reinterpret_cast<const float4*>(base + (size_t)kk * SDIM);
      vm[0][kk] = f2bf(a.x); vm[1][kk] = f2bf(a.y);
      vm[2][kk] = f2bf(a.z); vm[3][kk] = f2bf(a.w);
    }
    int swz_w = (r & 7) << 3;
#pragma unroll
    for (int mm = 0; mm < 4; ++mm) {
      int mloc = q * 4 + mm;
      int ebase = ((mloc * 16 + r) << 7) + k8 * 16;
      su8 lo, hi;
#pragma unroll
      for (int e = 0; e < 8; ++e) { lo[e] = vm[mm][e]; hi[e] = vm[mm][8 + e]; }
      *reinterpret_cast<su8*>(&sh[ebase ^ swz_w]) = lo;
      *reinterpret_cast<su8*>(&sh[(ebase + 8) ^ swz_w]) = hi;
    }
  }
  __syncthreads();

  int wave = tid >> 6, lane = tid & 63;
  int l15 = lane & 15, g = lane >> 4;
  int swz = (l15 & 7) << 3;
  int w4 = wave & 3, mgh = wave >> 2;      // j-quadrant, m-half
  int m0h = m0 + mgh * 8;
  const ushort* Lp = Lt + ((size_t)m0h * 32 + (size_t)w4 * 2) * 512 + (size_t)lane * 8;

  f32x4 st[2][8];
#pragma unroll
  for (int m = 0; m < 8; ++m) {
    int mloc = mgh * 8 + m;
    bf16x8 xf[4];
#pragma unroll
    for (int ks = 0; ks < 4; ++ks) {
      int e = ((mloc * 16 + l15) << 7) + ks * 32 + g * 8;
      xf[ks] = *reinterpret_cast<const bf16x8*>(&sh[e ^ swz]);
    }
    f32x4 a0 = {0.f, 0.f, 0.f, 0.f};
    f32x4 a1 = {0.f, 0.f, 0.f, 0.f};
#pragma unroll
    for (int ks = 0; ks < 4; ++ks) {
      bf16x8 l0 = *reinterpret_cast<const bf16x8*>(Lp + (size_t)((m * 4 + ks) * 8 + 0) * 512);
      bf16x8 l1 = *reinterpret_cast<const bf16x8*>(Lp + (size_t)((m * 4 + ks) * 8 + 1) * 512);
      a0 = __builtin_amdgcn_mfma_f32_16x16x32_bf16(xf[ks], l0, a0, 0, 0, 0);
      a1 = __builtin_amdgcn_mfma_f32_16x16x32_bf16(xf[ks], l1, a1, 0, 0, 0);
    }
    st[0][m] = a0;
    st[1][m] = a1;
  }

  int mg = mg2 * 2 + mgh;
  int ks1 = mg >> 2, g2 = mg & 3;
#pragma unroll
  for (int jt = 0; jt < 2; ++jt) {
    int j = w4 * 32 + jt * 16 + l15;
#pragma unroll
    for (int v = 0; v < 4; ++v) {
      int rr = g * 4 + v;
      su8 o;
      o[0] = f2bf(st[jt][0][v]); o[1] = f2bf(st[jt][1][v]);
      o[2] = f2bf(st[jt][2][v]); o[3] = f2bf(st[jt][3][v]);
      o[4] = f2bf(st[jt][4][v]); o[5] = f2bf(st[jt][5][v]);
      o[6] = f2bf(st[jt][6][v]); o[7] = f2bf(st[jt][7][v]);
      size_t a = (((size_t)(rt * 128 + j) * 4 + ks1) * 64 + g2 * 16 + rr) * 8;
      *reinterpret_cast<su8*>(T3 + a) = o;
    }
  }
}

// ======== stage2: 512 thr, jg = bid&7 pinned to XCD; grid = RT_PC*8 ========
// T3 slice staged via async global_load_lds. EPILOGUE VIA LDS BOUNCE:
// acc is scattered to sh then copied out with 4-consecutive-threads-per-line
// quartered stores (16 lines/instr, the R22 tag-rate fix applied to writes).
__global__ __launch_bounds__(512, 2) void k_s2(const ushort* __restrict__ T3,
                                               const ushort* __restrict__ Rt,
                                               float* __restrict__ out) {
  __shared__ __align__(16) ushort sh[32768];
  int tid = threadIdx.x;
  unsigned bid = blockIdx.x;
  int jg = bid & 7;
  int rt = bid >> 3;
  int row0 = rt * 16;
  int j0 = jg * 16;

  int wave = tid >> 6, lane = tid & 63;
  int l15 = lane & 15, g = lane >> 4;
  int ibase = wave * 16;

  {
    const ushort* s = T3 + (size_t)(rt * 128 + j0) * 4 * 512;
#if __has_builtin(__builtin_amdgcn_global_load_lds)
#pragma unroll
    for (int q = 0; q < 8; ++q) {
      int off = q * 512 + tid;
      __builtin_amdgcn_global_load_lds(
          (const __attribute__((address_space(1))) unsigned int*)(s + (size_t)off * 8),
          (__attribute__((address_space(3))) unsigned int*)(sh + (size_t)off * 8),
          16, 0, 0);
    }
#else
    const su8* s8 = reinterpret_cast<const su8*>(s);
    su8* d8 = reinterpret_cast<su8*>(sh);
#pragma unroll
    for (int q = 0; q < 8; ++q)
      d8[q * 512 + tid] = s8[q * 512 + tid];
#endif
  }
  __syncthreads();

  f32x4 acc[16];
#pragma unroll
  for (int jj = 0; jj < 16; ++jj) acc[jj] = {0.f, 0.f, 0.f, 0.f};

  const ushort* Rp = Rt + ((size_t)j0 * 32 + wave) * 512 + (size_t)lane * 8;
  const ushort* tp = sh + (size_t)lane * 8;

#pragma unroll
  for (int jj = 0; jj < 16; ++jj) {
#pragma unroll
    for (int ks = 0; ks < 4; ++ks) {
      bf16x8 af = *reinterpret_cast<const bf16x8*>(tp + (size_t)(jj * 4 + ks) * 512);
      bf16x8 bf = *reinterpret_cast<const bf16x8*>(Rp + (size_t)(jj * 32 + ks * 8) * 512);
      acc[jj] = __builtin_amdgcn_mfma_f32_16x16x32_bf16(af, bf, acc[jj], 0, 0, 0);
    }
  }

  // ---- epilogue: 2 phases x {scatter acc -> sh, barrier, quartered copy} ----
  // sh as f32[8][128][16]: [rs = g*2+v2][i][j-slot]; slot XOR (i&3) spreads banks.
  float* shf = reinterpret_cast<float*>(sh);
#pragma unroll
  for (int ph = 0; ph < 2; ++ph) {
    __syncthreads();               // af reads (ph0) / previous copy (ph1) complete
#pragma unroll
    for (int v2 = 0; v2 < 2; ++v2) {
      int v = ph * 2 + v2;
      int i = ibase + l15;
      int rs = g * 2 + v2;
      float* dl = shf + ((size_t)rs * 128 + i) * 16;
#pragma unroll
      for (int q = 0; q < 4; ++q) {
        f32x4 o; o[0] = acc[q * 4 + 0][v]; o[1] = acc[q * 4 + 1][v];
                 o[2] = acc[q * 4 + 2][v]; o[3] = acc[q * 4 + 3][v];
        *reinterpret_cast<f32x4*>(dl + ((q ^ (i & 3)) * 4)) = o;
      }
    }
    __syncthreads();
    // copy: 4096 16B tasks; 4 consecutive threads fill one 64B out line
#pragma unroll
    for (int it = 0; it < 8; ++it) {
      int task = it * 512 + tid;
      int rs = task >> 9;          // 0..7
      int rem = task & 511;
      int i = rem >> 2;            // 0..127
      int q = rem & 3;
      int row = row0 + (rs >> 1) * 4 + ph * 2 + (rs & 1);
      const float* sl = shf + ((size_t)rs * 128 + i) * 16 + ((q ^ (i & 3)) * 4);
      float* dg = out + (size_t)row * NCOL + (size_t)i * SDIM + j0 + q * 4;
      *reinterpret_cast<f32x4*>(dg) = *reinterpret_cast<const f32x4*>(sl);
    }
  }
}

extern "C" void kernel_launch(void* const* d_in, const int* in_sizes, int n_in,
                              void* d_out, int out_size, void* d_ws, size_t ws_size,
                              hipStream_t stream) {
  const float* x = (const float*)d_in[0];
  const float* L = (const float*)d_in[1];
  const float* R = (const float*)d_in[2];
  float* out = (float*)d_out;

  ushort* Lt = (ushort*)d_ws;
  ushort* Rt = Lt + 2097152;
  ushort* T3 = Rt + 2097152;      // 32 MB chunk buffer (cache-resident round-trip)

  k_prep<<<2048, 256, 0, stream>>>(L, R, Lt, Rt);

  for (int c = 0; c < NCHUNK; ++c) {
    const float* xc = x + (size_t)c * CHUNK * NCOL;
    float* oc = out + (size_t)c * CHUNK * NCOL;
    k_s1<<<dim3(RT_PC * 8), 512, 0, stream>>>(xc, Lt, T3);
    k_s2<<<dim3(RT_PC * 8), 512, 0, stream>>>(T3, Rt, oc);
  }
}

// Round 27
// 252.637 us; speedup vs baseline: 3.2225x; 1.0803x over previous
//
#include <hip/hip_runtime.h>
#include <hip/hip_bf16.h>

#define SDIM 128
#define NCOL 16384          // SDIM*SDIM
#define ROWS_TOTAL 4096
#define CHUNK 1024
#define RT_PC 64            // row-tiles per chunk
#define NCHUNK 4

using bf16x8 = __attribute__((ext_vector_type(8))) __bf16;
using su8    = __attribute__((ext_vector_type(8))) ushort;
using f32x4  = __attribute__((ext_vector_type(4))) float;

__device__ __forceinline__ ushort f2bf(float f) {
  __hip_bfloat16 h = __float2bfloat16(f);
  union { __hip_bfloat16 h; ushort u; } c; c.h = h;
  return c.u;
}

// ---- prep: L,R f32 -> bf16 in fragment-major layout ----
__global__ __launch_bounds__(256) void k_prep(const float* __restrict__ L,
                                              const float* __restrict__ R,
                                              ushort* __restrict__ Lt,
                                              ushort* __restrict__ Rt) {
  int id = blockIdx.x * 256 + threadIdx.x;
  const float* in = (id < 262144) ? L : R;
  ushort* outp    = (id < 262144) ? Lt : Rt;
  int t  = id & 262143;
  int t1 = t >> 11;
  int ks = (t >> 9) & 3;
  int tb = (t >> 6) & 7;
  int g  = (t >> 4) & 3;
  int tl = t & 15;
  const float* src = in + (size_t)(t1 * 128 + tb * 16 + tl) * 128 + ks * 32 + g * 8;
  float4 a = *reinterpret_cast<const float4*>(src);
  float4 b = *reinterpret_cast<const float4*>(src + 4);
  su8 o;
  o[0] = f2bf(a.x); o[1] = f2bf(a.y); o[2] = f2bf(a.z); o[3] = f2bf(a.w);
  o[4] = f2bf(b.x); o[5] = f2bf(b.y); o[6] = f2bf(b.z); o[7] = f2bf(b.w);
  *reinterpret_cast<su8*>(outp + (size_t)t * 8) = o;
}

// ======== stage1: 512 thr, block = 16 rows x 16 m (mg2 = bid&7 = XCD) ========
// Staging: 4 consecutive lanes read the 4 quarters of ONE 64B line (R22, -21us).
// T3 stores via LDS bounce + quartered copy (R26 pattern applied to writes).
__global__ __launch_bounds__(512, 2) void k_s1(const float* __restrict__ x,
                                               const ushort* __restrict__ Lt,
                                               ushort* __restrict__ T3) {
  __shared__ __align__(16) ushort sh[32768];
  int tid = threadIdx.x;
  unsigned bid = blockIdx.x;
  int mg2 = bid & 7;
  int rt  = bid >> 3;              // chunk-local
  int row0 = rt * 16;
  int m0 = mg2 * 16;

  // ---- stage x slice [16m][16r][128k] into LDS (f32->bf16), swizzled on r ----
  {
    int r  = tid >> 5;             // 0..15
    int q  = tid & 3;              // 16B quarter: m sub-block q*4..q*4+4
    int k8 = (tid >> 2) & 7;       // thread covers k = k8*16 .. k8*16+15
    const float* base = x + (size_t)(row0 + r) * NCOL + (size_t)(k8 * 16) * SDIM + m0 + q * 4;
    ushort vm[4][16];              // [mm][kk]
#pragma unroll
    for (int kk = 0; kk < 16; ++kk) {
      float4 a = *reinterpret_cast<const float4*>(base + (size_t)kk * SDIM);
      vm[0][kk] = f2bf(a.x); vm[1][kk] = f2bf(a.y);
      vm[2][kk] = f2bf(a.z); vm[3][kk] = f2bf(a.w);
    }
    int swz_w = (r & 7) << 3;
#pragma unroll
    for (int mm = 0; mm < 4; ++mm) {
      int mloc = q * 4 + mm;
      int ebase = ((mloc * 16 + r) << 7) + k8 * 16;
      su8 lo, hi;
#pragma unroll
      for (int e = 0; e < 8; ++e) { lo[e] = vm[mm][e]; hi[e] = vm[mm][8 + e]; }
      *reinterpret_cast<su8*>(&sh[ebase ^ swz_w]) = lo;
      *reinterpret_cast<su8*>(&sh[(ebase + 8) ^ swz_w]) = hi;
    }
  }
  __syncthreads();

  int wave = tid >> 6, lane = tid & 63;
  int l15 = lane & 15, g = lane >> 4;
  int swz = (l15 & 7) << 3;
  int w4 = wave & 3, mgh = wave >> 2;      // j-quadrant, m-half
  int m0h = m0 + mgh * 8;
  const ushort* Lp = Lt + ((size_t)m0h * 32 + (size_t)w4 * 2) * 512 + (size_t)lane * 8;

  f32x4 st[2][8];
#pragma unroll
  for (int m = 0; m < 8; ++m) {
    int mloc = mgh * 8 + m;
    bf16x8 xf[4];
#pragma unroll
    for (int ks = 0; ks < 4; ++ks) {
      int e = ((mloc * 16 + l15) << 7) + ks * 32 + g * 8;
      xf[ks] = *reinterpret_cast<const bf16x8*>(&sh[e ^ swz]);
    }
    f32x4 a0 = {0.f, 0.f, 0.f, 0.f};
    f32x4 a1 = {0.f, 0.f, 0.f, 0.f};
#pragma unroll
    for (int ks = 0; ks < 4; ++ks) {
      bf16x8 l0 = *reinterpret_cast<const bf16x8*>(Lp + (size_t)((m * 4 + ks) * 8 + 0) * 512);
      bf16x8 l1 = *reinterpret_cast<const bf16x8*>(Lp + (size_t)((m * 4 + ks) * 8 + 1) * 512);
      a0 = __builtin_amdgcn_mfma_f32_16x16x32_bf16(xf[ks], l0, a0, 0, 0, 0);
      a1 = __builtin_amdgcn_mfma_f32_16x16x32_bf16(xf[ks], l1, a1, 0, 0, 0);
    }
    st[0][m] = a0;
    st[1][m] = a1;
  }

  // ---- epilogue via LDS bounce: sh = [j 128][mgh 2][slot 16][8], slot XOR ((j&3)<<1) ----
  __syncthreads();                 // all xs reads done before overwrite
#pragma unroll
  for (int jt = 0; jt < 2; ++jt) {
    int j = w4 * 32 + jt * 16 + l15;
#pragma unroll
    for (int v = 0; v < 4; ++v) {
      int slot = (g * 4 + v) ^ ((j & 3) << 1);
      su8 o;
      o[0] = f2bf(st[jt][0][v]); o[1] = f2bf(st[jt][1][v]);
      o[2] = f2bf(st[jt][2][v]); o[3] = f2bf(st[jt][3][v]);
      o[4] = f2bf(st[jt][4][v]); o[5] = f2bf(st[jt][5][v]);
      o[6] = f2bf(st[jt][6][v]); o[7] = f2bf(st[jt][7][v]);
      *reinterpret_cast<su8*>(&sh[(((size_t)j * 2 + mgh) * 16 + slot) * 8]) = o;
    }
  }
  __syncthreads();
  // quartered copy: 4096 16B tasks; 4 consecutive threads fill one 64B T3 line.
#pragma unroll
  for (int it = 0; it < 8; ++it) {
    int task = it * 512 + tid;
    int j    = task >> 5;          // 0..127
    int unit = task & 31;
    int mghc = unit >> 4;          // 0..1
    int slot = unit & 15;
    int mgc  = mg2 * 2 + mghc;
    int ks1c = mgc >> 2, g2c = mgc & 3;
    const ushort* sl = &sh[(((size_t)j * 2 + mghc) * 16 + (slot ^ ((j & 3) << 1))) * 8];
    size_t a = (((size_t)(rt * 128 + j) * 4 + ks1c) * 64 + g2c * 16 + slot) * 8;
    *reinterpret_cast<su8*>(T3 + a) = *reinterpret_cast<const su8*>(sl);
  }
}

// ======== stage2: 512 thr, jg = bid&7 pinned to XCD; grid = RT_PC*8 ========
// T3 slice staged via async global_load_lds; epilogue via LDS bounce (R26, -27us).
__global__ __launch_bounds__(512, 2) void k_s2(const ushort* __restrict__ T3,
                                               const ushort* __restrict__ Rt,
                                               float* __restrict__ out) {
  __shared__ __align__(16) ushort sh[32768];
  int tid = threadIdx.x;
  unsigned bid = blockIdx.x;
  int jg = bid & 7;
  int rt = bid >> 3;
  int row0 = rt * 16;
  int j0 = jg * 16;

  int wave = tid >> 6, lane = tid & 63;
  int l15 = lane & 15, g = lane >> 4;
  int ibase = wave * 16;

  {
    const ushort* s = T3 + (size_t)(rt * 128 + j0) * 4 * 512;
#if __has_builtin(__builtin_amdgcn_global_load_lds)
#pragma unroll
    for (int q = 0; q < 8; ++q) {
      int off = q * 512 + tid;
      __builtin_amdgcn_global_load_lds(
          (const __attribute__((address_space(1))) unsigned int*)(s + (size_t)off * 8),
          (__attribute__((address_space(3))) unsigned int*)(sh + (size_t)off * 8),
          16, 0, 0);
    }
#else
    const su8* s8 = reinterpret_cast<const su8*>(s);
    su8* d8 = reinterpret_cast<su8*>(sh);
#pragma unroll
    for (int q = 0; q < 8; ++q)
      d8[q * 512 + tid] = s8[q * 512 + tid];
#endif
  }
  __syncthreads();

  f32x4 acc[16];
#pragma unroll
  for (int jj = 0; jj < 16; ++jj) acc[jj] = {0.f, 0.f, 0.f, 0.f};

  const ushort* Rp = Rt + ((size_t)j0 * 32 + wave) * 512 + (size_t)lane * 8;
  const ushort* tp = sh + (size_t)lane * 8;

#pragma unroll
  for (int jj = 0; jj < 16; ++jj) {
#pragma unroll
    for (int ks = 0; ks < 4; ++ks) {
      bf16x8 af = *reinterpret_cast<const bf16x8*>(tp + (size_t)(jj * 4 + ks) * 512);
      bf16x8 bf = *reinterpret_cast<const bf16x8*>(Rp + (size_t)(jj * 32 + ks * 8) * 512);
      acc[jj] = __builtin_amdgcn_mfma_f32_16x16x32_bf16(af, bf, acc[jj], 0, 0, 0);
    }
  }

  // ---- epilogue: 2 phases x {scatter acc -> sh, barrier, quartered copy} ----
  float* shf = reinterpret_cast<float*>(sh);
#pragma unroll
  for (int ph = 0; ph < 2; ++ph) {
    __syncthreads();
#pragma unroll
    for (int v2 = 0; v2 < 2; ++v2) {
      int v = ph * 2 + v2;
      int i = ibase + l15;
      int rs = g * 2 + v2;
      float* dl = shf + ((size_t)rs * 128 + i) * 16;
#pragma unroll
      for (int q = 0; q < 4; ++q) {
        f32x4 o; o[0] = acc[q * 4 + 0][v]; o[1] = acc[q * 4 + 1][v];
                 o[2] = acc[q * 4 + 2][v]; o[3] = acc[q * 4 + 3][v];
        *reinterpret_cast<f32x4*>(dl + ((q ^ (i & 3)) * 4)) = o;
      }
    }
    __syncthreads();
#pragma unroll
    for (int it = 0; it < 8; ++it) {
      int task = it * 512 + tid;
      int rs = task >> 9;
      int rem = task & 511;
      int i = rem >> 2;
      int q = rem & 3;
      int row = row0 + (rs >> 1) * 4 + ph * 2 + (rs & 1);
      const float* sl = shf + ((size_t)rs * 128 + i) * 16 + ((q ^ (i & 3)) * 4);
      float* dg = out + (size_t)row * NCOL + (size_t)i * SDIM + j0 + q * 4;
      *reinterpret_cast<f32x4*>(dg) = *reinterpret_cast<const f32x4*>(sl);
    }
  }
}

extern "C" void kernel_launch(void* const* d_in, const int* in_sizes, int n_in,
                              void* d_out, int out_size, void* d_ws, size_t ws_size,
                              hipStream_t stream) {
  const float* x = (const float*)d_in[0];
  const float* L = (const float*)d_in[1];
  const float* R = (const float*)d_in[2];
  float* out = (float*)d_out;

  ushort* Lt = (ushort*)d_ws;
  ushort* Rt = Lt + 2097152;
  ushort* T3 = Rt + 2097152;      // 32 MB chunk buffer (cache-resident round-trip)

  k_prep<<<2048, 256, 0, stream>>>(L, R, Lt, Rt);

  for (int c = 0; c < NCHUNK; ++c) {
    const float* xc = x + (size_t)c * CHUNK * NCOL;
    float* oc = out + (size_t)c * CHUNK * NCOL;
    k_s1<<<dim3(RT_PC * 8), 512, 0, stream>>>(xc, Lt, T3);
    k_s2<<<dim3(RT_PC * 8), 512, 0, stream>>>(T3, Rt, oc);
  }
}

// Round 28
// 248.507 us; speedup vs baseline: 3.2761x; 1.0166x over previous
//
#include <hip/hip_runtime.h>
#include <hip/hip_bf16.h>

#define SDIM 128
#define NCOL 16384          // SDIM*SDIM
#define ROWS_TOTAL 4096
#define CHUNK 1024
#define RT_PC 64            // row-tiles per chunk
#define NCHUNK 4

using bf16x8 = __attribute__((ext_vector_type(8))) __bf16;
using su8    = __attribute__((ext_vector_type(8))) ushort;
using f32x4  = __attribute__((ext_vector_type(4))) float;

__device__ __forceinline__ ushort f2bf(float f) {
  __hip_bfloat16 h = __float2bfloat16(f);
  union { __hip_bfloat16 h; ushort u; } c; c.h = h;
  return c.u;
}

// ---- prep: L,R f32 -> bf16 in fragment-major layout ----
__global__ __launch_bounds__(256) void k_prep(const float* __restrict__ L,
                                              const float* __restrict__ R,
                                              ushort* __restrict__ Lt,
                                              ushort* __restrict__ Rt) {
  int id = blockIdx.x * 256 + threadIdx.x;
  const float* in = (id < 262144) ? L : R;
  ushort* outp    = (id < 262144) ? Lt : Rt;
  int t  = id & 262143;
  int t1 = t >> 11;
  int ks = (t >> 9) & 3;
  int tb = (t >> 6) & 7;
  int g  = (t >> 4) & 3;
  int tl = t & 15;
  const float* src = in + (size_t)(t1 * 128 + tb * 16 + tl) * 128 + ks * 32 + g * 8;
  float4 a = *reinterpret_cast<const float4*>(src);
  float4 b = *reinterpret_cast<const float4*>(src + 4);
  su8 o;
  o[0] = f2bf(a.x); o[1] = f2bf(a.y); o[2] = f2bf(a.z); o[3] = f2bf(a.w);
  o[4] = f2bf(b.x); o[5] = f2bf(b.y); o[6] = f2bf(b.z); o[7] = f2bf(b.w);
  *reinterpret_cast<su8*>(outp + (size_t)t * 8) = o;
}

// ======== stage1: 512 thr, block = 16 rows x 16 m (mg2 = bid&7 = XCD) ========
// Staging: quartered line reads (R22). T3 stores: LDS bounce + quartered (R27).
__global__ __launch_bounds__(512, 2) void k_s1(const float* __restrict__ x,
                                               const ushort* __restrict__ Lt,
                                               ushort* __restrict__ T3) {
  __shared__ __align__(16) ushort sh[32768];
  int tid = threadIdx.x;
  unsigned bid = blockIdx.x;
  int mg2 = bid & 7;
  int rt  = bid >> 3;              // chunk-local
  int row0 = rt * 16;
  int m0 = mg2 * 16;

  // ---- stage x slice [16m][16r][128k] into LDS (f32->bf16), swizzled on r ----
  {
    int r  = tid >> 5;             // 0..15
    int q  = tid & 3;              // 16B quarter: m sub-block q*4..q*4+4
    int k8 = (tid >> 2) & 7;       // thread covers k = k8*16 .. k8*16+15
    const float* base = x + (size_t)(row0 + r) * NCOL + (size_t)(k8 * 16) * SDIM + m0 + q * 4;
    ushort vm[4][16];              // [mm][kk]
#pragma unroll
    for (int kk = 0; kk < 16; ++kk) {
      float4 a = *reinterpret_cast<const float4*>(base + (size_t)kk * SDIM);
      vm[0][kk] = f2bf(a.x); vm[1][kk] = f2bf(a.y);
      vm[2][kk] = f2bf(a.z); vm[3][kk] = f2bf(a.w);
    }
    int swz_w = (r & 7) << 3;
#pragma unroll
    for (int mm = 0; mm < 4; ++mm) {
      int mloc = q * 4 + mm;
      int ebase = ((mloc * 16 + r) << 7) + k8 * 16;
      su8 lo, hi;
#pragma unroll
      for (int e = 0; e < 8; ++e) { lo[e] = vm[mm][e]; hi[e] = vm[mm][8 + e]; }
      *reinterpret_cast<su8*>(&sh[ebase ^ swz_w]) = lo;
      *reinterpret_cast<su8*>(&sh[(ebase + 8) ^ swz_w]) = hi;
    }
  }
  __syncthreads();

  int wave = tid >> 6, lane = tid & 63;
  int l15 = lane & 15, g = lane >> 4;
  int swz = (l15 & 7) << 3;
  int w4 = wave & 3, mgh = wave >> 2;      // j-quadrant, m-half
  int m0h = m0 + mgh * 8;
  const ushort* Lp = Lt + ((size_t)m0h * 32 + (size_t)w4 * 2) * 512 + (size_t)lane * 8;

  f32x4 st[2][8];
#pragma unroll
  for (int m = 0; m < 8; ++m) {
    int mloc = mgh * 8 + m;
    bf16x8 xf[4];
#pragma unroll
    for (int ks = 0; ks < 4; ++ks) {
      int e = ((mloc * 16 + l15) << 7) + ks * 32 + g * 8;
      xf[ks] = *reinterpret_cast<const bf16x8*>(&sh[e ^ swz]);
    }
    f32x4 a0 = {0.f, 0.f, 0.f, 0.f};
    f32x4 a1 = {0.f, 0.f, 0.f, 0.f};
#pragma unroll
    for (int ks = 0; ks < 4; ++ks) {
      bf16x8 l0 = *reinterpret_cast<const bf16x8*>(Lp + (size_t)((m * 4 + ks) * 8 + 0) * 512);
      bf16x8 l1 = *reinterpret_cast<const bf16x8*>(Lp + (size_t)((m * 4 + ks) * 8 + 1) * 512);
      a0 = __builtin_amdgcn_mfma_f32_16x16x32_bf16(xf[ks], l0, a0, 0, 0, 0);
      a1 = __builtin_amdgcn_mfma_f32_16x16x32_bf16(xf[ks], l1, a1, 0, 0, 0);
    }
    st[0][m] = a0;
    st[1][m] = a1;
  }

  // ---- epilogue via LDS bounce: sh = [j 128][mgh 2][slot 16][8], slot XOR ((j&3)<<1) ----
  __syncthreads();
#pragma unroll
  for (int jt = 0; jt < 2; ++jt) {
    int j = w4 * 32 + jt * 16 + l15;
#pragma unroll
    for (int v = 0; v < 4; ++v) {
      int slot = (g * 4 + v) ^ ((j & 3) << 1);
      su8 o;
      o[0] = f2bf(st[jt][0][v]); o[1] = f2bf(st[jt][1][v]);
      o[2] = f2bf(st[jt][2][v]); o[3] = f2bf(st[jt][3][v]);
      o[4] = f2bf(st[jt][4][v]); o[5] = f2bf(st[jt][5][v]);
      o[6] = f2bf(st[jt][6][v]); o[7] = f2bf(st[jt][7][v]);
      *reinterpret_cast<su8*>(&sh[(((size_t)j * 2 + mgh) * 16 + slot) * 8]) = o;
    }
  }
  __syncthreads();
#pragma unroll
  for (int it = 0; it < 8; ++it) {
    int task = it * 512 + tid;
    int j    = task >> 5;          // 0..127
    int unit = task & 31;
    int mghc = unit >> 4;          // 0..1
    int slot = unit & 15;
    int mgc  = mg2 * 2 + mghc;
    int ks1c = mgc >> 2, g2c = mgc & 3;
    const ushort* sl = &sh[(((size_t)j * 2 + mghc) * 16 + (slot ^ ((j & 3) << 1))) * 8];
    size_t a = (((size_t)(rt * 128 + j) * 4 + ks1c) * 64 + g2c * 16 + slot) * 8;
    *reinterpret_cast<su8*>(T3 + a) = *reinterpret_cast<const su8*>(sl);
  }
}

// ======== stage2: 512 thr, jg = bid&7 pinned to XCD; grid = RT_PC*8 ========
// LDS HALVED to 32 KB -> up to 4 blocks/CU (VGPR ~64). T3 staged/computed in
// two 32KB halves; epilogue bounce in 4 x 32KB phases.
__global__ __launch_bounds__(512, 4) void k_s2(const ushort* __restrict__ T3,
                                               const ushort* __restrict__ Rt,
                                               float* __restrict__ out) {
  __shared__ __align__(16) ushort sh[16384];   // 32 KB
  int tid = threadIdx.x;
  unsigned bid = blockIdx.x;
  int jg = bid & 7;
  int rt = bid >> 3;
  int row0 = rt * 16;
  int j0 = jg * 16;

  int wave = tid >> 6, lane = tid & 63;
  int l15 = lane & 15, g = lane >> 4;
  int ibase = wave * 16;

  const ushort* s = T3 + (size_t)(rt * 128 + j0) * 4 * 512;
  const ushort* Rp = Rt + ((size_t)j0 * 32 + wave) * 512 + (size_t)lane * 8;
  const ushort* tp = sh + (size_t)lane * 8;

  f32x4 acc[16];
#pragma unroll
  for (int jj = 0; jj < 16; ++jj) acc[jj] = {0.f, 0.f, 0.f, 0.f};

#pragma unroll
  for (int h = 0; h < 2; ++h) {
    if (h) __syncthreads();        // all h0 af reads done before overwrite
    // ---- stage 32KB half h ----
#if __has_builtin(__builtin_amdgcn_global_load_lds)
#pragma unroll
    for (int q = 0; q < 4; ++q) {
      int src_off = (h * 4 + q) * 512 + tid;   // 16B units in T3 slice
      int dst_off = q * 512 + tid;
      __builtin_amdgcn_global_load_lds(
          (const __attribute__((address_space(1))) unsigned int*)(s + (size_t)src_off * 8),
          (__attribute__((address_space(3))) unsigned int*)(sh + (size_t)dst_off * 8),
          16, 0, 0);
    }
#else
    {
      const su8* s8 = reinterpret_cast<const su8*>(s);
      su8* d8 = reinterpret_cast<su8*>(sh);
#pragma unroll
      for (int q = 0; q < 4; ++q)
        d8[q * 512 + tid] = s8[(h * 4 + q) * 512 + tid];
    }
#endif
    __syncthreads();
    // ---- compute jj h*8 .. h*8+7 ----
#pragma unroll
    for (int jl = 0; jl < 8; ++jl) {
      int jj = h * 8 + jl;
#pragma unroll
      for (int ks = 0; ks < 4; ++ks) {
        bf16x8 af = *reinterpret_cast<const bf16x8*>(tp + (size_t)(jl * 4 + ks) * 512);
        bf16x8 bf = *reinterpret_cast<const bf16x8*>(Rp + (size_t)(jj * 32 + ks * 8) * 512);
        acc[jj] = __builtin_amdgcn_mfma_f32_16x16x32_bf16(af, bf, acc[jj], 0, 0, 0);
      }
    }
  }

  // ---- epilogue: 4 phases x {scatter acc(v=ph) -> sh (32KB), barrier, copy} ----
  float* shf = reinterpret_cast<float*>(sh);
#pragma unroll
  for (int ph = 0; ph < 4; ++ph) {
    __syncthreads();               // af reads (ph0) / previous copy done
    {
      int i = ibase + l15;
      float* dl = shf + ((size_t)g * 128 + i) * 16;
#pragma unroll
      for (int q = 0; q < 4; ++q) {
        f32x4 o; o[0] = acc[q * 4 + 0][ph]; o[1] = acc[q * 4 + 1][ph];
                 o[2] = acc[q * 4 + 2][ph]; o[3] = acc[q * 4 + 3][ph];
        *reinterpret_cast<f32x4*>(dl + ((q ^ (i & 3)) * 4)) = o;
      }
    }
    __syncthreads();
    // copy: 2048 16B tasks; 4 consecutive threads fill one 64B out line
#pragma unroll
    for (int it = 0; it < 4; ++it) {
      int task = it * 512 + tid;
      int rs = task >> 9;          // 0..3
      int rem = task & 511;
      int i = rem >> 2;            // 0..127
      int q = rem & 3;
      int row = row0 + rs * 4 + ph;
      const float* sl = shf + ((size_t)rs * 128 + i) * 16 + ((q ^ (i & 3)) * 4);
      float* dg = out + (size_t)row * NCOL + (size_t)i * SDIM + j0 + q * 4;
      *reinterpret_cast<f32x4*>(dg) = *reinterpret_cast<const f32x4*>(sl);
    }
  }
}

extern "C" void kernel_launch(void* const* d_in, const int* in_sizes, int n_in,
                              void* d_out, int out_size, void* d_ws, size_t ws_size,
                              hipStream_t stream) {
  const float* x = (const float*)d_in[0];
  const float* L = (const float*)d_in[1];
  const float* R = (const float*)d_in[2];
  float* out = (float*)d_out;

  ushort* Lt = (ushort*)d_ws;
  ushort* Rt = Lt + 2097152;
  ushort* T3 = Rt + 2097152;      // 32 MB chunk buffer (cache-resident round-trip)

  k_prep<<<2048, 256, 0, stream>>>(L, R, Lt, Rt);

  for (int c = 0; c < NCHUNK; ++c) {
    const float* xc = x + (size_t)c * CHUNK * NCOL;
    float* oc = out + (size_t)c * CHUNK * NCOL;
    k_s1<<<dim3(RT_PC * 8), 512, 0, stream>>>(xc, Lt, T3);
    k_s2<<<dim3(RT_PC * 8), 512, 0, stream>>>(T3, Rt, oc);
  }
}